// Round 1
// baseline (2817.166 us; speedup 1.0000x reference)
//
#include <hip/hip_runtime.h>

#define EPS 1e-5f
#define SLOPE 0.1f
#define DIM 128
#define DE 64
#define RNUM 7

__device__ __forceinline__ float lrelu(float x) { return x >= 0.f ? x : SLOPE * x; }
__device__ __forceinline__ void atomAddF(float* p, float v) { unsafeAtomicAdd(p, v); }

// ---------------- column stats: out[0..F) = sum, out[F..2F) = sumsq ----------------
template<int F, int BLK>
__global__ void colstats(const float* __restrict__ x, int nrows, float* __restrict__ out) {
  constexpr int G = BLK / F;
  int f = threadIdx.x % F;
  int g = threadIdx.x / F;
  float s = 0.f, q = 0.f;
  for (int r = blockIdx.x * G + g; r < nrows; r += gridDim.x * G) {
    float v = x[(size_t)r * F + f];
    s += v; q += v * v;
  }
  if constexpr (G > 1) {
    __shared__ float ls[BLK], lq[BLK];
    ls[threadIdx.x] = s; lq[threadIdx.x] = q;
    __syncthreads();
    if (g == 0) {
      #pragma unroll
      for (int i = 1; i < G; i++) { s += ls[i * F + f]; q += lq[i * F + f]; }
    }
  }
  if (g == 0) { atomAddF(&out[f], s); atomAddF(&out[F + f], q); }
}

// ---------------- y = lrelu(bn(xin)) @ W (+bias) (+resid); optional col-stats of y ---
// 128 threads, 32 rows/block. Thread t: cols 4*(t&31)..+3, rows 8*(t>>5)..+7.
template<bool HAS_BIAS, bool RESID, bool STATS>
__global__ __launch_bounds__(128) void mlp128(
    const float* __restrict__ xin, const float* __restrict__ W,
    const float* __restrict__ bias,
    const float* __restrict__ bng, const float* __restrict__ bnb,
    const float* __restrict__ stats_in, float invN, int N,
    const float* __restrict__ resid,
    float* __restrict__ out, float* __restrict__ stats_out) {
  __shared__ float tile[32 * DIM];
  int t = threadIdx.x;
  float a, c;
  {
    float mean = stats_in[t] * invN;
    float var = stats_in[DIM + t] * invN - mean * mean;
    a = bng[t] * rsqrtf(var + EPS);
    c = bnb[t] - mean * a;
  }
  int r0 = blockIdx.x * 32;
  int nr = min(32, N - r0);
  for (int r = 0; r < 32; r++) {
    float v = 0.f;
    if (r < nr) {
      v = xin[(size_t)(r0 + r) * DIM + t];
      v = lrelu(v * a + c);
    }
    tile[r * DIM + t] = v;
  }
  __syncthreads();
  int cg = t & 31, rg = t >> 5;
  float acc[8][4];
  #pragma unroll
  for (int rr = 0; rr < 8; rr++) { acc[rr][0]=0.f; acc[rr][1]=0.f; acc[rr][2]=0.f; acc[rr][3]=0.f; }
  const float4* W4 = (const float4*)W;
  #pragma unroll 2
  for (int k = 0; k < DIM; k += 4) {
    float4 w0 = W4[(k + 0) * 32 + cg];
    float4 w1 = W4[(k + 1) * 32 + cg];
    float4 w2 = W4[(k + 2) * 32 + cg];
    float4 w3 = W4[(k + 3) * 32 + cg];
    #pragma unroll
    for (int rr = 0; rr < 8; rr++) {
      float4 tv = *(const float4*)&tile[(rg * 8 + rr) * DIM + k];
      acc[rr][0] += tv.x * w0.x + tv.y * w1.x + tv.z * w2.x + tv.w * w3.x;
      acc[rr][1] += tv.x * w0.y + tv.y * w1.y + tv.z * w2.y + tv.w * w3.y;
      acc[rr][2] += tv.x * w0.z + tv.y * w1.z + tv.z * w2.z + tv.w * w3.z;
      acc[rr][3] += tv.x * w0.w + tv.y * w1.w + tv.z * w2.w + tv.w * w3.w;
    }
  }
  float4 bv = make_float4(0.f, 0.f, 0.f, 0.f);
  if (HAS_BIAS) bv = ((const float4*)bias)[cg];
  float s0=0,s1=0,s2=0,s3=0,q0=0,q1=0,q2=0,q3=0;
  #pragma unroll
  for (int rr = 0; rr < 8; rr++) {
    int r = rg * 8 + rr;
    if (r < nr) {
      float o0 = acc[rr][0] + bv.x;
      float o1 = acc[rr][1] + bv.y;
      float o2 = acc[rr][2] + bv.z;
      float o3 = acc[rr][3] + bv.w;
      if (RESID) {
        const float4 rv = *(const float4*)&resid[(size_t)(r0 + r) * DIM + cg * 4];
        o0 += rv.x; o1 += rv.y; o2 += rv.z; o3 += rv.w;
      }
      *(float4*)&out[(size_t)(r0 + r) * DIM + cg * 4] = make_float4(o0, o1, o2, o3);
      if (STATS) {
        s0 += o0; q0 += o0 * o0; s1 += o1; q1 += o1 * o1;
        s2 += o2; q2 += o2 * o2; s3 += o3; q3 += o3 * o3;
      }
    }
  }
  if (STATS) {
    __syncthreads();                 // tile reads done; reuse tile for reduction
    float* reds = tile;
    float* redq = tile + 512;
    int col = cg * 4;
    reds[rg * DIM + col + 0] = s0; reds[rg * DIM + col + 1] = s1;
    reds[rg * DIM + col + 2] = s2; reds[rg * DIM + col + 3] = s3;
    redq[rg * DIM + col + 0] = q0; redq[rg * DIM + col + 1] = q1;
    redq[rg * DIM + col + 2] = q2; redq[rg * DIM + col + 3] = q3;
    __syncthreads();
    if (rg == 0) {
      #pragma unroll
      for (int cc = 0; cc < 4; cc++) {
        int cl = col + cc;
        float ss = reds[cl] + reds[DIM + cl] + reds[2 * DIM + cl] + reds[3 * DIM + cl];
        float qq = redq[cl] + redq[DIM + cl] + redq[2 * DIM + cl] + redq[3 * DIM + cl];
        atomAddF(&stats_out[cl], ss);
        atomAddF(&stats_out[DIM + cl], qq);
      }
    }
  }
}

// ---------------- out1 = lrelu(bn896(update)) @ lin_W ; col-stats of out1 ----------
__global__ __launch_bounds__(128) void lin_mlp(
    const float* __restrict__ upd, const float* __restrict__ W,
    const float* __restrict__ bng, const float* __restrict__ bnb,
    const float* __restrict__ stats_in, float invN, int N,
    float* __restrict__ out, float* __restrict__ stats_out) {
  __shared__ float tile[32 * DIM];
  int t = threadIdx.x;
  int r0 = blockIdx.x * 32;
  int nr = min(32, N - r0);
  int cg = t & 31, rg = t >> 5;
  float acc[8][4];
  #pragma unroll
  for (int rr = 0; rr < 8; rr++) { acc[rr][0]=0.f; acc[rr][1]=0.f; acc[rr][2]=0.f; acc[rr][3]=0.f; }
  const float4* W4 = (const float4*)W;
  for (int kt = 0; kt < RNUM; kt++) {
    int cb = kt * DIM;
    float a, c;
    {
      int col = cb + t;
      float mean = stats_in[col] * invN;
      float var = stats_in[RNUM * DIM + col] * invN - mean * mean;
      a = bng[col] * rsqrtf(var + EPS);
      c = bnb[col] - mean * a;
    }
    for (int r = 0; r < 32; r++) {
      float v = 0.f;
      if (r < nr) {
        v = upd[(size_t)(r0 + r) * (RNUM * DIM) + cb + t];
        v = lrelu(v * a + c);
      }
      tile[r * DIM + t] = v;
    }
    __syncthreads();
    #pragma unroll 2
    for (int k = 0; k < DIM; k += 4) {
      float4 w0 = W4[(cb + k + 0) * 32 + cg];
      float4 w1 = W4[(cb + k + 1) * 32 + cg];
      float4 w2 = W4[(cb + k + 2) * 32 + cg];
      float4 w3 = W4[(cb + k + 3) * 32 + cg];
      #pragma unroll
      for (int rr = 0; rr < 8; rr++) {
        float4 tv = *(const float4*)&tile[(rg * 8 + rr) * DIM + k];
        acc[rr][0] += tv.x * w0.x + tv.y * w1.x + tv.z * w2.x + tv.w * w3.x;
        acc[rr][1] += tv.x * w0.y + tv.y * w1.y + tv.z * w2.y + tv.w * w3.y;
        acc[rr][2] += tv.x * w0.z + tv.y * w1.z + tv.z * w2.z + tv.w * w3.z;
        acc[rr][3] += tv.x * w0.w + tv.y * w1.w + tv.z * w2.w + tv.w * w3.w;
      }
    }
    __syncthreads();
  }
  float s0=0,s1=0,s2=0,s3=0,q0=0,q1=0,q2=0,q3=0;
  #pragma unroll
  for (int rr = 0; rr < 8; rr++) {
    int r = rg * 8 + rr;
    if (r < nr) {
      float o0 = acc[rr][0], o1 = acc[rr][1], o2 = acc[rr][2], o3 = acc[rr][3];
      *(float4*)&out[(size_t)(r0 + r) * DIM + cg * 4] = make_float4(o0, o1, o2, o3);
      s0 += o0; q0 += o0 * o0; s1 += o1; q1 += o1 * o1;
      s2 += o2; q2 += o2 * o2; s3 += o3; q3 += o3 * o3;
    }
  }
  __syncthreads();
  float* reds = tile;
  float* redq = tile + 512;
  int col = cg * 4;
  reds[rg * DIM + col + 0] = s0; reds[rg * DIM + col + 1] = s1;
  reds[rg * DIM + col + 2] = s2; reds[rg * DIM + col + 3] = s3;
  redq[rg * DIM + col + 0] = q0; redq[rg * DIM + col + 1] = q1;
  redq[rg * DIM + col + 2] = q2; redq[rg * DIM + col + 3] = q3;
  __syncthreads();
  if (rg == 0) {
    #pragma unroll
    for (int cc = 0; cc < 4; cc++) {
      int cl = col + cc;
      float ss = reds[cl] + reds[DIM + cl] + reds[2 * DIM + cl] + reds[3 * DIM + cl];
      float qq = redq[cl] + redq[DIM + cl] + redq[2 * DIM + cl] + redq[3 * DIM + cl];
      atomAddF(&stats_out[cl], ss);
      atomAddF(&stats_out[DIM + cl], qq);
    }
  }
}

// ---------------- Gram of Y = lrelu(bn1(h_e)): G = Y^T Y (64x64) and colsum(Y) -----
__global__ __launch_bounds__(256) void gram_kernel(
    const float* __restrict__ he, int E,
    const float* __restrict__ g1, const float* __restrict__ b1,
    const float* __restrict__ s_he, float invE,
    float* __restrict__ gram, float* __restrict__ gcol, int tilesPerBlock) {
  __shared__ float yt[32 * DE];
  int t = threadIdx.x;
  int f = t & 63;
  float a, c;
  {
    float mean = s_he[f] * invE;
    float var = s_he[DE + f] * invE - mean * mean;
    a = g1[f] * rsqrtf(var + EPS);
    c = b1[f] - mean * a;
  }
  int k1b = t >> 4, k2b = t & 15;
  float accG[4][4];
  #pragma unroll
  for (int i = 0; i < 4; i++) { accG[i][0]=0.f; accG[i][1]=0.f; accG[i][2]=0.f; accG[i][3]=0.f; }
  float colsum = 0.f;
  long long tile0 = (long long)blockIdx.x * tilesPerBlock;
  for (int tt = 0; tt < tilesPerBlock; tt++) {
    int e0 = (int)((tile0 + tt) * 32);
    if (e0 >= E) break;
    __syncthreads();
    #pragma unroll
    for (int i = 0; i < 8; i++) {
      int r = (t + i * 256) >> 6;
      int e = e0 + r;
      float v = 0.f;
      if (e < E) v = lrelu(he[(size_t)e * DE + f] * a + c);
      yt[r * DE + f] = v;
      colsum += v;
    }
    __syncthreads();
    #pragma unroll 4
    for (int r = 0; r < 32; r++) {
      float4 ya = *(const float4*)&yt[r * DE + k1b * 4];
      float4 yb = *(const float4*)&yt[r * DE + k2b * 4];
      accG[0][0] += ya.x * yb.x; accG[0][1] += ya.x * yb.y; accG[0][2] += ya.x * yb.z; accG[0][3] += ya.x * yb.w;
      accG[1][0] += ya.y * yb.x; accG[1][1] += ya.y * yb.y; accG[1][2] += ya.y * yb.z; accG[1][3] += ya.y * yb.w;
      accG[2][0] += ya.z * yb.x; accG[2][1] += ya.z * yb.y; accG[2][2] += ya.z * yb.z; accG[2][3] += ya.z * yb.w;
      accG[3][0] += ya.w * yb.x; accG[3][1] += ya.w * yb.y; accG[3][2] += ya.w * yb.z; accG[3][3] += ya.w * yb.w;
    }
  }
  #pragma unroll
  for (int i = 0; i < 4; i++) {
    #pragma unroll
    for (int j = 0; j < 4; j++)
      atomAddF(&gram[(k1b * 4 + i) * DE + k2b * 4 + j], accG[i][j]);
  }
  atomAddF(&gcol[f], colsum);
}

// ---------------- edge-BN2 analytic stats: q_j = w_j^T G w_j / E, m1_j = wbar.w_j ---
__global__ __launch_bounds__(128) void ebn2_partial(
    const float* __restrict__ gram, const float* __restrict__ gcol,
    const float* __restrict__ eW, float invE,
    float* __restrict__ q, float* __restrict__ m1) {
  int j = threadIdx.x;
  int k1 = blockIdx.x;
  float wk1 = eW[k1 * DIM + j];
  float s = 0.f;
  for (int k2 = 0; k2 < DE; k2++) s += eW[k2 * DIM + j] * gram[k1 * DE + k2];
  atomAddF(&q[j], wk1 * s * invE);
  if (k1 == 0) {
    float m = 0.f;
    for (int k = 0; k < DE; k++) m += gcol[k] * eW[k * DIM + j];
    m1[j] = m * invE;
  }
}

// ---------------- fused: edge GEMM + bn2 + lrelu + gather(x path) + atomic scatter --
__global__ __launch_bounds__(128) void edge_kernel(
    const float* __restrict__ he, const int* __restrict__ nin,
    const int* __restrict__ nout, const int* __restrict__ rel,
    const float* __restrict__ eW, const float* __restrict__ ebias,
    const float* __restrict__ eg1, const float* __restrict__ eb1,
    const float* __restrict__ s_he, float invE,
    const float* __restrict__ q, const float* __restrict__ m1,
    const float* __restrict__ eg2, const float* __restrict__ eb2,
    const float* __restrict__ x1, const float* __restrict__ s_x1,
    const float* __restrict__ ig2, const float* __restrict__ ib2, float invN,
    int E, float* __restrict__ upd, int tilesPerBlock) {
  __shared__ float yt[32 * DE];
  __shared__ float a2s[DIM], c2s[DIM], ax2s[DIM], cx2s[DIM];
  __shared__ int sseg[32], sgin[32];
  int t = threadIdx.x;
  {
    float m1v = m1[t];
    float mean = m1v + ebias[t];
    float var = q[t] - m1v * m1v;
    float aa = eg2[t] * rsqrtf(var + EPS);
    a2s[t] = aa;
    c2s[t] = aa * ebias[t] + eb2[t] - mean * aa;   // bias folded into affine
    float mx = s_x1[t] * invN;
    float vx = s_x1[DIM + t] * invN - mx * mx;
    float ax = ig2[t] * rsqrtf(vx + EPS);
    ax2s[t] = ax;
    cx2s[t] = ib2[t] - mx * ax;
  }
  int f = t & 63;
  float ae1, ce1;
  {
    float me = s_he[f] * invE;
    float ve = s_he[DE + f] * invE - me * me;
    ae1 = eg1[f] * rsqrtf(ve + EPS);
    ce1 = eb1[f] - me * ae1;
  }
  int cg = t & 31, rg = t >> 5;
  long long tile0 = (long long)blockIdx.x * tilesPerBlock;
  for (int tt = 0; tt < tilesPerBlock; tt++) {
    int e0 = (int)((tile0 + tt) * 32);
    if (e0 >= E) break;
    __syncthreads();   // prev-iter reads done (also covers initial coeff writes)
    if (t < 32) {
      int e = e0 + t;
      sgin[t] = (e < E) ? nin[e] : 0;
      sseg[t] = (e < E) ? (nout[e] * RNUM + rel[e]) : -1;
    }
    #pragma unroll
    for (int i = 0; i < 16; i++) {
      int r = (t + i * 128) >> 6;
      int e = e0 + r;
      float v = 0.f;
      if (e < E) v = lrelu(he[(size_t)e * DE + f] * ae1 + ce1);
      yt[r * DE + f] = v;
    }
    __syncthreads();
    float acc[8][4];
    #pragma unroll
    for (int rr = 0; rr < 8; rr++) { acc[rr][0]=0.f; acc[rr][1]=0.f; acc[rr][2]=0.f; acc[rr][3]=0.f; }
    const float4* W4 = (const float4*)eW;
    #pragma unroll 2
    for (int k = 0; k < DE; k += 4) {
      float4 w0 = W4[(k + 0) * 32 + cg];
      float4 w1 = W4[(k + 1) * 32 + cg];
      float4 w2 = W4[(k + 2) * 32 + cg];
      float4 w3 = W4[(k + 3) * 32 + cg];
      #pragma unroll
      for (int rr = 0; rr < 8; rr++) {
        float4 tv = *(const float4*)&yt[(rg * 8 + rr) * DE + k];
        acc[rr][0] += tv.x * w0.x + tv.y * w1.x + tv.z * w2.x + tv.w * w3.x;
        acc[rr][1] += tv.x * w0.y + tv.y * w1.y + tv.z * w2.y + tv.w * w3.y;
        acc[rr][2] += tv.x * w0.z + tv.y * w1.z + tv.z * w2.z + tv.w * w3.z;
        acc[rr][3] += tv.x * w0.w + tv.y * w1.w + tv.z * w2.w + tv.w * w3.w;
      }
    }
    float4 a2 = *(const float4*)&a2s[cg * 4];
    float4 c2 = *(const float4*)&c2s[cg * 4];
    float4 ax = *(const float4*)&ax2s[cg * 4];
    float4 cx = *(const float4*)&cx2s[cg * 4];
    #pragma unroll
    for (int rr = 0; rr < 8; rr++) {
      int r = rg * 8 + rr;
      if (e0 + r < E) {
        int seg = sseg[r], gi = sgin[r];
        float4 xv = *(const float4*)&x1[(size_t)gi * DIM + cg * 4];
        float v0 = lrelu(acc[rr][0] * a2.x + c2.x) + lrelu(xv.x * ax.x + cx.x);
        float v1 = lrelu(acc[rr][1] * a2.y + c2.y) + lrelu(xv.y * ax.y + cx.y);
        float v2 = lrelu(acc[rr][2] * a2.z + c2.z) + lrelu(xv.z * ax.z + cx.z);
        float v3 = lrelu(acc[rr][3] * a2.w + c2.w) + lrelu(xv.w * ax.w + cx.w);
        float* dst = &upd[(size_t)seg * DIM + cg * 4];
        atomAddF(dst + 0, v0);
        atomAddF(dst + 1, v1);
        atomAddF(dst + 2, v2);
        atomAddF(dst + 3, v3);
      }
    }
  }
}

extern "C" void kernel_launch(void* const* d_in, const int* in_sizes, int n_in,
                              void* d_out, int out_size, void* d_ws, size_t ws_size,
                              hipStream_t stream) {
  const float* h_v      = (const float*)d_in[0];
  const int*   node_in  = (const int*)d_in[1];
  const int*   node_out = (const int*)d_in[2];
  const int*   rel      = (const int*)d_in[3];
  const float* h_e      = (const float*)d_in[4];
  const float* in_bn1_g = (const float*)d_in[5];
  const float* in_bn1_b = (const float*)d_in[6];
  const float* in_W     = (const float*)d_in[7];
  const float* in_b     = (const float*)d_in[8];
  const float* in_bn2_g = (const float*)d_in[9];
  const float* in_bn2_b = (const float*)d_in[10];
  const float* e_bn1_g  = (const float*)d_in[11];
  const float* e_bn1_b  = (const float*)d_in[12];
  const float* e_W      = (const float*)d_in[13];
  const float* e_b      = (const float*)d_in[14];
  const float* e_bn2_g  = (const float*)d_in[15];
  const float* e_bn2_b  = (const float*)d_in[16];
  const float* lin_bn_g = (const float*)d_in[17];
  const float* lin_bn_b = (const float*)d_in[18];
  const float* lin_W    = (const float*)d_in[19];
  const float* out_bn_g = (const float*)d_in[20];
  const float* out_bn_b = (const float*)d_in[21];
  const float* out_W    = (const float*)d_in[22];

  int N = in_sizes[0] / DIM;
  int E = in_sizes[1];
  if (N <= 0 || E <= 0) return;
  float invN = 1.f / (float)N;
  float invE = 1.f / (float)E;

  // workspace layout
  float* ws   = (float*)d_ws;
  float* upd  = ws;                                   // N * 7 * 128
  float* x1   = upd + (size_t)N * RNUM * DIM;         // N * 128 (reused as out1)
  float* stats = x1 + (size_t)N * DIM;
  float* s_hv = stats;            // 256
  float* s_x1 = s_hv + 2 * DIM;   // 256
  float* s_he = s_x1 + 2 * DIM;   // 128
  float* gram = s_he + 2 * DE;    // 4096
  float* gcol = gram + DE * DE;   // 64
  float* qv   = gcol + DE;        // 128
  float* m1v  = qv + DIM;         // 128
  float* s_up = m1v + DIM;        // 1792
  float* s_o1 = s_up + 2 * RNUM * DIM; // 256
  size_t statsFloats = (size_t)(s_o1 + 2 * DIM - stats);

  hipMemsetAsync(upd, 0, (size_t)N * RNUM * DIM * sizeof(float), stream);
  hipMemsetAsync(stats, 0, statsFloats * sizeof(float), stream);

  int nBlk32 = (N + 31) / 32;

  // 1) col stats of h_v
  colstats<DIM, 256><<<512, 256, 0, stream>>>(h_v, N, s_hv);
  // 2) x1 = lrelu(bn1(h_v)) @ in_W + in_b ; stats of x1
  mlp128<true, false, true><<<nBlk32, 128, 0, stream>>>(
      h_v, in_W, in_b, in_bn1_g, in_bn1_b, s_hv, invN, N, nullptr, x1, s_x1);
  // 3) col stats of h_e
  colstats<DE, 256><<<1024, 256, 0, stream>>>(h_e, E, s_he);
  // 4) Gram of Y = lrelu(bn1(h_e))
  {
    int tiles = 16;
    int blocks = (E + 32 * tiles - 1) / (32 * tiles);
    gram_kernel<<<blocks, 256, 0, stream>>>(h_e, E, e_bn1_g, e_bn1_b, s_he, invE,
                                            gram, gcol, tiles);
  }
  // 5) analytic edge-bn2 stats
  ebn2_partial<<<DE, 128, 0, stream>>>(gram, gcol, e_W, invE, qv, m1v);
  // 6) fused edge GEMM + gather + scatter
  {
    int tiles = 4;
    int blocks = (E + 32 * tiles - 1) / (32 * tiles);
    edge_kernel<<<blocks, 128, 0, stream>>>(
        h_e, node_in, node_out, rel, e_W, e_b, e_bn1_g, e_bn1_b, s_he, invE,
        qv, m1v, e_bn2_g, e_bn2_b, x1, s_x1, in_bn2_g, in_bn2_b, invN,
        E, upd, tiles);
  }
  // 7) col stats of update [N, 896]
  colstats<RNUM * DIM, RNUM * DIM><<<448, RNUM * DIM, 0, stream>>>(upd, N, s_up);
  // 8) out1 = lrelu(bn896(update)) @ lin_W ; stats of out1 (out1 reuses x1 buffer)
  lin_mlp<<<nBlk32, 128, 0, stream>>>(upd, lin_W, lin_bn_g, lin_bn_b, s_up, invN, N,
                                      x1, s_o1);
  // 9) out = lrelu(bn(out1)) @ out_W + h_v
  mlp128<false, true, false><<<nBlk32, 128, 0, stream>>>(
      x1, out_W, nullptr, out_bn_g, out_bn_b, s_o1, invN, N, h_v, (float*)d_out, nullptr);
}

// Round 2
// 2098.876 us; speedup vs baseline: 1.3422x; 1.3422x over previous
//
#include <hip/hip_runtime.h>

#define EPS 1e-5f
#define SLOPE 0.1f
#define DIM 128
#define DE 64
#define RNUM 7
#define RD (RNUM * DIM)   // 896
#define NPB 4             // nodes per block in fused scatter

__device__ __forceinline__ float lrelu(float x) { return x >= 0.f ? x : SLOPE * x; }
__device__ __forceinline__ void atomAddF(float* p, float v) { unsafeAtomicAdd(p, v); }

// ---------------- column stats: out[0..F) = sum, out[F..2F) = sumsq ----------------
template<int F, int BLK>
__global__ void colstats(const float* __restrict__ x, int nrows, float* __restrict__ out) {
  constexpr int G = BLK / F;
  int f = threadIdx.x % F;
  int g = threadIdx.x / F;
  float s = 0.f, q = 0.f;
  for (int r = blockIdx.x * G + g; r < nrows; r += gridDim.x * G) {
    float v = x[(size_t)r * F + f];
    s += v; q += v * v;
  }
  if constexpr (G > 1) {
    __shared__ float ls[BLK], lq[BLK];
    ls[threadIdx.x] = s; lq[threadIdx.x] = q;
    __syncthreads();
    if (g == 0) {
      #pragma unroll
      for (int i = 1; i < G; i++) { s += ls[i * F + f]; q += lq[i * F + f]; }
    }
  }
  if (g == 0) { atomAddF(&out[f], s); atomAddF(&out[F + f], q); }
}

// ---------------- y = lrelu(bn(xin)) @ W (+bias) (+resid); optional col-stats of y ---
template<bool HAS_BIAS, bool RESID, bool STATS>
__global__ __launch_bounds__(128) void mlp128(
    const float* __restrict__ xin, const float* __restrict__ W,
    const float* __restrict__ bias,
    const float* __restrict__ bng, const float* __restrict__ bnb,
    const float* __restrict__ stats_in, float invN, int N,
    const float* __restrict__ resid,
    float* __restrict__ out, float* __restrict__ stats_out) {
  __shared__ float tile[32 * DIM];
  int t = threadIdx.x;
  float a, c;
  {
    float mean = stats_in[t] * invN;
    float var = stats_in[DIM + t] * invN - mean * mean;
    a = bng[t] * rsqrtf(var + EPS);
    c = bnb[t] - mean * a;
  }
  int r0 = blockIdx.x * 32;
  int nr = min(32, N - r0);
  for (int r = 0; r < 32; r++) {
    float v = 0.f;
    if (r < nr) {
      v = xin[(size_t)(r0 + r) * DIM + t];
      v = lrelu(v * a + c);
    }
    tile[r * DIM + t] = v;
  }
  __syncthreads();
  int cg = t & 31, rg = t >> 5;
  float acc[8][4];
  #pragma unroll
  for (int rr = 0; rr < 8; rr++) { acc[rr][0]=0.f; acc[rr][1]=0.f; acc[rr][2]=0.f; acc[rr][3]=0.f; }
  const float4* W4 = (const float4*)W;
  #pragma unroll 2
  for (int k = 0; k < DIM; k += 4) {
    float4 w0 = W4[(k + 0) * 32 + cg];
    float4 w1 = W4[(k + 1) * 32 + cg];
    float4 w2 = W4[(k + 2) * 32 + cg];
    float4 w3 = W4[(k + 3) * 32 + cg];
    #pragma unroll
    for (int rr = 0; rr < 8; rr++) {
      float4 tv = *(const float4*)&tile[(rg * 8 + rr) * DIM + k];
      acc[rr][0] += tv.x * w0.x + tv.y * w1.x + tv.z * w2.x + tv.w * w3.x;
      acc[rr][1] += tv.x * w0.y + tv.y * w1.y + tv.z * w2.y + tv.w * w3.y;
      acc[rr][2] += tv.x * w0.z + tv.y * w1.z + tv.z * w2.z + tv.w * w3.z;
      acc[rr][3] += tv.x * w0.w + tv.y * w1.w + tv.z * w2.w + tv.w * w3.w;
    }
  }
  float4 bv = make_float4(0.f, 0.f, 0.f, 0.f);
  if (HAS_BIAS) bv = ((const float4*)bias)[cg];
  float s0=0,s1=0,s2=0,s3=0,q0=0,q1=0,q2=0,q3=0;
  #pragma unroll
  for (int rr = 0; rr < 8; rr++) {
    int r = rg * 8 + rr;
    if (r < nr) {
      float o0 = acc[rr][0] + bv.x;
      float o1 = acc[rr][1] + bv.y;
      float o2 = acc[rr][2] + bv.z;
      float o3 = acc[rr][3] + bv.w;
      if (RESID) {
        const float4 rv = *(const float4*)&resid[(size_t)(r0 + r) * DIM + cg * 4];
        o0 += rv.x; o1 += rv.y; o2 += rv.z; o3 += rv.w;
      }
      *(float4*)&out[(size_t)(r0 + r) * DIM + cg * 4] = make_float4(o0, o1, o2, o3);
      if (STATS) {
        s0 += o0; q0 += o0 * o0; s1 += o1; q1 += o1 * o1;
        s2 += o2; q2 += o2 * o2; s3 += o3; q3 += o3 * o3;
      }
    }
  }
  if (STATS) {
    __syncthreads();
    float* reds = tile;
    float* redq = tile + 512;
    int col = cg * 4;
    reds[rg * DIM + col + 0] = s0; reds[rg * DIM + col + 1] = s1;
    reds[rg * DIM + col + 2] = s2; reds[rg * DIM + col + 3] = s3;
    redq[rg * DIM + col + 0] = q0; redq[rg * DIM + col + 1] = q1;
    redq[rg * DIM + col + 2] = q2; redq[rg * DIM + col + 3] = q3;
    __syncthreads();
    if (rg == 0) {
      #pragma unroll
      for (int cc = 0; cc < 4; cc++) {
        int cl = col + cc;
        float ss = reds[cl] + reds[DIM + cl] + reds[2 * DIM + cl] + reds[3 * DIM + cl];
        float qq = redq[cl] + redq[DIM + cl] + redq[2 * DIM + cl] + redq[3 * DIM + cl];
        atomAddF(&stats_out[cl], ss);
        atomAddF(&stats_out[DIM + cl], qq);
      }
    }
  }
}

// ---------------- x2 = lrelu(bn2(x1)) in-place --------------------------------------
__global__ __launch_bounds__(256) void x2k(float* __restrict__ x1,
    const float* __restrict__ s_x1, const float* __restrict__ g,
    const float* __restrict__ b, float invN, int total4) {
  int i = blockIdx.x * 256 + threadIdx.x;
  if (i >= total4) return;
  int col = (i & 31) * 4;
  float4 v = ((float4*)x1)[i];
  float m0 = s_x1[col + 0] * invN, m1 = s_x1[col + 1] * invN;
  float m2 = s_x1[col + 2] * invN, m3 = s_x1[col + 3] * invN;
  float a0 = g[col + 0] * rsqrtf(s_x1[DIM + col + 0] * invN - m0 * m0 + EPS);
  float a1 = g[col + 1] * rsqrtf(s_x1[DIM + col + 1] * invN - m1 * m1 + EPS);
  float a2 = g[col + 2] * rsqrtf(s_x1[DIM + col + 2] * invN - m2 * m2 + EPS);
  float a3 = g[col + 3] * rsqrtf(s_x1[DIM + col + 3] * invN - m3 * m3 + EPS);
  v.x = lrelu(v.x * a0 + (b[col + 0] - m0 * a0));
  v.y = lrelu(v.y * a1 + (b[col + 1] - m1 * a1));
  v.z = lrelu(v.z * a2 + (b[col + 2] - m2 * a2));
  v.w = lrelu(v.w * a3 + (b[col + 3] - m3 * a3));
  ((float4*)x1)[i] = v;
}

// ---------------- out1 = lrelu(bn896(update)) @ lin_W ; col-stats of out1 ----------
__global__ __launch_bounds__(128) void lin_mlp(
    const float* __restrict__ upd, const float* __restrict__ W,
    const float* __restrict__ bng, const float* __restrict__ bnb,
    const float* __restrict__ stats_in, float invN, int N,
    float* __restrict__ out, float* __restrict__ stats_out) {
  __shared__ float tile[32 * DIM];
  int t = threadIdx.x;
  int r0 = blockIdx.x * 32;
  int nr = min(32, N - r0);
  int cg = t & 31, rg = t >> 5;
  float acc[8][4];
  #pragma unroll
  for (int rr = 0; rr < 8; rr++) { acc[rr][0]=0.f; acc[rr][1]=0.f; acc[rr][2]=0.f; acc[rr][3]=0.f; }
  const float4* W4 = (const float4*)W;
  for (int kt = 0; kt < RNUM; kt++) {
    int cb = kt * DIM;
    float a, c;
    {
      int col = cb + t;
      float mean = stats_in[col] * invN;
      float var = stats_in[RD + col] * invN - mean * mean;
      a = bng[col] * rsqrtf(var + EPS);
      c = bnb[col] - mean * a;
    }
    for (int r = 0; r < 32; r++) {
      float v = 0.f;
      if (r < nr) {
        v = upd[(size_t)(r0 + r) * RD + cb + t];
        v = lrelu(v * a + c);
      }
      tile[r * DIM + t] = v;
    }
    __syncthreads();
    #pragma unroll 2
    for (int k = 0; k < DIM; k += 4) {
      float4 w0 = W4[(cb + k + 0) * 32 + cg];
      float4 w1 = W4[(cb + k + 1) * 32 + cg];
      float4 w2 = W4[(cb + k + 2) * 32 + cg];
      float4 w3 = W4[(cb + k + 3) * 32 + cg];
      #pragma unroll
      for (int rr = 0; rr < 8; rr++) {
        float4 tv = *(const float4*)&tile[(rg * 8 + rr) * DIM + k];
        acc[rr][0] += tv.x * w0.x + tv.y * w1.x + tv.z * w2.x + tv.w * w3.x;
        acc[rr][1] += tv.x * w0.y + tv.y * w1.y + tv.z * w2.y + tv.w * w3.y;
        acc[rr][2] += tv.x * w0.z + tv.y * w1.z + tv.z * w2.z + tv.w * w3.z;
        acc[rr][3] += tv.x * w0.w + tv.y * w1.w + tv.z * w2.w + tv.w * w3.w;
      }
    }
    __syncthreads();
  }
  float s0=0,s1=0,s2=0,s3=0,q0=0,q1=0,q2=0,q3=0;
  #pragma unroll
  for (int rr = 0; rr < 8; rr++) {
    int r = rg * 8 + rr;
    if (r < nr) {
      float o0 = acc[rr][0], o1 = acc[rr][1], o2 = acc[rr][2], o3 = acc[rr][3];
      *(float4*)&out[(size_t)(r0 + r) * DIM + cg * 4] = make_float4(o0, o1, o2, o3);
      s0 += o0; q0 += o0 * o0; s1 += o1; q1 += o1 * o1;
      s2 += o2; q2 += o2 * o2; s3 += o3; q3 += o3 * o3;
    }
  }
  __syncthreads();
  float* reds = tile;
  float* redq = tile + 512;
  int col = cg * 4;
  reds[rg * DIM + col + 0] = s0; reds[rg * DIM + col + 1] = s1;
  reds[rg * DIM + col + 2] = s2; reds[rg * DIM + col + 3] = s3;
  redq[rg * DIM + col + 0] = q0; redq[rg * DIM + col + 1] = q1;
  redq[rg * DIM + col + 2] = q2; redq[rg * DIM + col + 3] = q3;
  __syncthreads();
  if (rg == 0) {
    #pragma unroll
    for (int cc = 0; cc < 4; cc++) {
      int cl = col + cc;
      float ss = reds[cl] + reds[DIM + cl] + reds[2 * DIM + cl] + reds[3 * DIM + cl];
      float qq = redq[cl] + redq[DIM + cl] + redq[2 * DIM + cl] + redq[3 * DIM + cl];
      atomAddF(&stats_out[cl], ss);
      atomAddF(&stats_out[DIM + cl], qq);
    }
  }
}

// ---------------- Gram of Y = lrelu(bn1(h_e)): per-block partials (no atomics) -----
__global__ __launch_bounds__(256) void gram_kernel(
    const float* __restrict__ he, int E,
    const float* __restrict__ g1, const float* __restrict__ b1,
    const float* __restrict__ s_he, float invE,
    float* __restrict__ parts, int tilesPerBlock) {
  __shared__ float yt[32 * DE];
  int t = threadIdx.x;
  int f = t & 63;
  float a, c;
  {
    float mean = s_he[f] * invE;
    float var = s_he[DE + f] * invE - mean * mean;
    a = g1[f] * rsqrtf(var + EPS);
    c = b1[f] - mean * a;
  }
  int k1b = t >> 4, k2b = t & 15;
  float accG[4][4];
  #pragma unroll
  for (int i = 0; i < 4; i++) { accG[i][0]=0.f; accG[i][1]=0.f; accG[i][2]=0.f; accG[i][3]=0.f; }
  float colsum = 0.f;
  long long tile0 = (long long)blockIdx.x * tilesPerBlock;
  for (int tt = 0; tt < tilesPerBlock; tt++) {
    int e0 = (int)((tile0 + tt) * 32);
    if (e0 >= E) break;
    __syncthreads();
    #pragma unroll
    for (int i = 0; i < 8; i++) {
      int r = (t + i * 256) >> 6;
      int e = e0 + r;
      float v = 0.f;
      if (e < E) v = lrelu(he[(size_t)e * DE + f] * a + c);
      yt[r * DE + f] = v;
      colsum += v;
    }
    __syncthreads();
    #pragma unroll 4
    for (int r = 0; r < 32; r++) {
      float4 ya = *(const float4*)&yt[r * DE + k1b * 4];
      float4 yb = *(const float4*)&yt[r * DE + k2b * 4];
      accG[0][0] += ya.x * yb.x; accG[0][1] += ya.x * yb.y; accG[0][2] += ya.x * yb.z; accG[0][3] += ya.x * yb.w;
      accG[1][0] += ya.y * yb.x; accG[1][1] += ya.y * yb.y; accG[1][2] += ya.y * yb.z; accG[1][3] += ya.y * yb.w;
      accG[2][0] += ya.z * yb.x; accG[2][1] += ya.z * yb.y; accG[2][2] += ya.z * yb.z; accG[2][3] += ya.z * yb.w;
      accG[3][0] += ya.w * yb.x; accG[3][1] += ya.w * yb.y; accG[3][2] += ya.w * yb.z; accG[3][3] += ya.w * yb.w;
    }
  }
  __syncthreads();
  yt[t] = colsum;
  __syncthreads();
  float* outp = parts + (size_t)blockIdx.x * 4160;
  #pragma unroll
  for (int i = 0; i < 4; i++)
    #pragma unroll
    for (int j = 0; j < 4; j++)
      outp[(k1b * 4 + i) * DE + k2b * 4 + j] = accG[i][j];
  if (t < DE) outp[4096 + t] = yt[t] + yt[t + 64] + yt[t + 128] + yt[t + 192];
}

__global__ __launch_bounds__(256) void gram_reduce(const float* __restrict__ parts, int P,
    float* __restrict__ gram, float* __restrict__ gcol) {
  int j = blockIdx.x * 256 + threadIdx.x;
  if (j >= 4160) return;
  float s = 0.f;
  for (int p = 0; p < P; p++) s += parts[(size_t)p * 4160 + j];
  if (j < 4096) gram[j] = s; else gcol[j - 4096] = s;
}

// ---------------- edge-BN2 analytic stats: q_j = w_j^T G w_j / E, m1_j = wbar.w_j ---
__global__ __launch_bounds__(128) void ebn2_partial(
    const float* __restrict__ gram, const float* __restrict__ gcol,
    const float* __restrict__ eW, float invE,
    float* __restrict__ q, float* __restrict__ m1) {
  int j = threadIdx.x;
  int k1 = blockIdx.x;
  float wk1 = eW[k1 * DIM + j];
  float s = 0.f;
  for (int k2 = 0; k2 < DE; k2++) s += eW[k2 * DIM + j] * gram[k1 * DE + k2];
  atomAddF(&q[j], wk1 * s * invE);
  if (k1 == 0) {
    float m = 0.f;
    for (int k = 0; k < DE; k++) m += gcol[k] * eW[k * DIM + j];
    m1[j] = m * invE;
  }
}

// ---------------- CSR build -------------------------------------------------------
__global__ void count_k(const int* __restrict__ nout, int E, int* __restrict__ cnt) {
  for (int e = blockIdx.x * blockDim.x + threadIdx.x; e < E; e += gridDim.x * blockDim.x)
    atomicAdd(&cnt[nout[e]], 1);
}

__global__ __launch_bounds__(256) void scan1(const int* __restrict__ in, int n,
    int* __restrict__ excl, int* __restrict__ sums) {
  __shared__ int s[256];
  int i = blockIdx.x * 256 + threadIdx.x;
  int v = (i < n) ? in[i] : 0;
  s[threadIdx.x] = v; __syncthreads();
  for (int off = 1; off < 256; off <<= 1) {
    int x = (threadIdx.x >= off) ? s[threadIdx.x - off] : 0;
    __syncthreads(); s[threadIdx.x] += x; __syncthreads();
  }
  if (i < n) excl[i] = s[threadIdx.x] - v;
  if (threadIdx.x == 255) sums[blockIdx.x] = s[255];
}

__global__ __launch_bounds__(1024) void scan2(int* __restrict__ sums, int nch) {
  __shared__ int s[1024];
  int t = threadIdx.x;
  int v = (t < nch) ? sums[t] : 0;
  s[t] = v; __syncthreads();
  for (int off = 1; off < 1024; off <<= 1) {
    int x = (t >= off) ? s[t - off] : 0;
    __syncthreads(); s[t] += x; __syncthreads();
  }
  if (t < nch) sums[t] = s[t] - v;
}

__global__ __launch_bounds__(256) void scan3(const int* __restrict__ excl,
    const int* __restrict__ sums, int n, int E,
    int* __restrict__ base, int* __restrict__ cursor) {
  int i = blockIdx.x * 256 + threadIdx.x;
  if (i < n) { int b = excl[i] + sums[blockIdx.x]; base[i] = b; cursor[i] = b; }
  if (i == 0) base[n] = E;
}

__global__ void scatter_k(const int* __restrict__ nout, const int* __restrict__ nin,
    const int* __restrict__ rel, int E, int* __restrict__ cursor, int2* __restrict__ elist2) {
  for (int e = blockIdx.x * blockDim.x + threadIdx.x; e < E; e += gridDim.x * blockDim.x) {
    int n = nout[e];
    int pos = atomicAdd(&cursor[n], 1);
    elist2[pos] = make_int2(e, (nin[e] << 3) | rel[e]);
  }
}

// ---------------- fused: sorted-edge GEMM + bn2 + lrelu + x2 gather + LDS scatter --
__global__ __launch_bounds__(128) void fused_edge_scatter(
    const float* __restrict__ he, const int2* __restrict__ elist2,
    const int* __restrict__ base, const float* __restrict__ eW,
    const float* __restrict__ eg1, const float* __restrict__ eb1,
    const float* __restrict__ s_he, float invE,
    const float* __restrict__ qv, const float* __restrict__ m1v,
    const float* __restrict__ eg2, const float* __restrict__ eb2,
    const float* __restrict__ x2, int N, float* __restrict__ upd) {
  __shared__ float accs[NPB * RD];     // 14336 B per-node accumulators
  __shared__ float yt[32 * DE];        // 8192 B edge-Y tile
  __shared__ float a2s[DIM], c2s[DIM];
  __shared__ int s_eid[32], s_nl[32], s_gr[32];
  int t = threadIdx.x;
  int n0 = blockIdx.x * NPB;
  int f = t & 63;
  float ae1, ce1;
  {
    float me = s_he[f] * invE;
    float ve = s_he[DE + f] * invE - me * me;
    ae1 = eg1[f] * rsqrtf(ve + EPS);
    ce1 = eb1[f] - me * ae1;
  }
  {
    float m = m1v[t];
    float a = eg2[t] * rsqrtf(qv[t] - m * m + EPS);
    a2s[t] = a;
    c2s[t] = eb2[t] - m * a;   // e_b bias cancels through BN
  }
  for (int i = t; i < NPB * RD; i += 128) accs[i] = 0.f;
  int estart = base[n0];
  int eend = base[min(n0 + NPB, N)];
  int bb1 = base[min(n0 + 1, N)];
  int bb2 = base[min(n0 + 2, N)];
  int bb3 = base[min(n0 + 3, N)];
  __syncthreads();
  int cg = t & 31, rg = t >> 5;
  const float4* W4 = (const float4*)eW;
  for (int e0 = estart; e0 < eend; e0 += 32) {
    if (t < 32) {
      int pos = e0 + t;
      int2 ee = (pos < eend) ? elist2[pos] : make_int2(0, 0);
      s_eid[t] = ee.x;
      s_gr[t] = ee.y;
      s_nl[t] = (pos >= bb3) ? 3 : (pos >= bb2) ? 2 : (pos >= bb1) ? 1 : 0;
    }
    __syncthreads();
    #pragma unroll
    for (int i = 0; i < 16; i++) {
      int r = (t + i * 128) >> 6;
      float v = 0.f;
      if (e0 + r < eend) v = lrelu(he[(size_t)s_eid[r] * DE + f] * ae1 + ce1);
      yt[r * DE + f] = v;
    }
    __syncthreads();
    float a8[8][4];
    #pragma unroll
    for (int rr = 0; rr < 8; rr++) { a8[rr][0]=0.f; a8[rr][1]=0.f; a8[rr][2]=0.f; a8[rr][3]=0.f; }
    #pragma unroll 2
    for (int k = 0; k < DE; k += 4) {
      float4 w0 = W4[(k + 0) * 32 + cg];
      float4 w1 = W4[(k + 1) * 32 + cg];
      float4 w2 = W4[(k + 2) * 32 + cg];
      float4 w3 = W4[(k + 3) * 32 + cg];
      #pragma unroll
      for (int rr = 0; rr < 8; rr++) {
        float4 tv = *(const float4*)&yt[(rg * 8 + rr) * DE + k];
        a8[rr][0] += tv.x * w0.x + tv.y * w1.x + tv.z * w2.x + tv.w * w3.x;
        a8[rr][1] += tv.x * w0.y + tv.y * w1.y + tv.z * w2.y + tv.w * w3.y;
        a8[rr][2] += tv.x * w0.z + tv.y * w1.z + tv.z * w2.z + tv.w * w3.z;
        a8[rr][3] += tv.x * w0.w + tv.y * w1.w + tv.z * w2.w + tv.w * w3.w;
      }
    }
    float4 a2 = *(const float4*)&a2s[cg * 4];
    float4 c2 = *(const float4*)&c2s[cg * 4];
    int aoff[8];
    #pragma unroll
    for (int rr = 0; rr < 8; rr++) {
      int r = rg * 8 + rr;
      if (e0 + r < eend) {
        int gr = s_gr[r];
        const float4 xv = *(const float4*)&x2[(size_t)(gr >> 3) * DIM + cg * 4];
        a8[rr][0] = lrelu(a8[rr][0] * a2.x + c2.x) + xv.x;
        a8[rr][1] = lrelu(a8[rr][1] * a2.y + c2.y) + xv.y;
        a8[rr][2] = lrelu(a8[rr][2] * a2.z + c2.z) + xv.z;
        a8[rr][3] = lrelu(a8[rr][3] * a2.w + c2.w) + xv.w;
        aoff[rr] = s_nl[r] * RD + (gr & 7) * DIM + cg * 4;
      } else aoff[rr] = -1;
    }
    // 4-phase race-free LDS accumulate (threads sharing cols are rg-partitioned)
    #pragma unroll
    for (int p = 0; p < 4; p++) {
      if (rg == p) {
        #pragma unroll
        for (int rr = 0; rr < 8; rr++) {
          int o = aoff[rr];
          if (o >= 0) {
            accs[o + 0] += a8[rr][0];
            accs[o + 1] += a8[rr][1];
            accs[o + 2] += a8[rr][2];
            accs[o + 3] += a8[rr][3];
          }
        }
      }
      __syncthreads();
    }
  }
  int nn = min(NPB, N - n0);
  for (int i = t; i < nn * RD; i += 128)
    upd[(size_t)n0 * RD + i] = accs[i];
}

extern "C" void kernel_launch(void* const* d_in, const int* in_sizes, int n_in,
                              void* d_out, int out_size, void* d_ws, size_t ws_size,
                              hipStream_t stream) {
  const float* h_v      = (const float*)d_in[0];
  const int*   node_in  = (const int*)d_in[1];
  const int*   node_out = (const int*)d_in[2];
  const int*   rel      = (const int*)d_in[3];
  const float* h_e      = (const float*)d_in[4];
  const float* in_bn1_g = (const float*)d_in[5];
  const float* in_bn1_b = (const float*)d_in[6];
  const float* in_W     = (const float*)d_in[7];
  const float* in_b     = (const float*)d_in[8];
  const float* in_bn2_g = (const float*)d_in[9];
  const float* in_bn2_b = (const float*)d_in[10];
  const float* e_bn1_g  = (const float*)d_in[11];
  const float* e_bn1_b  = (const float*)d_in[12];
  const float* e_W      = (const float*)d_in[13];
  // const float* e_b   = (const float*)d_in[14];  // cancels through edge bn2
  const float* e_bn2_g  = (const float*)d_in[15];
  const float* e_bn2_b  = (const float*)d_in[16];
  const float* lin_bn_g = (const float*)d_in[17];
  const float* lin_bn_b = (const float*)d_in[18];
  const float* lin_W    = (const float*)d_in[19];
  const float* out_bn_g = (const float*)d_in[20];
  const float* out_bn_b = (const float*)d_in[21];
  const float* out_W    = (const float*)d_in[22];

  int N = in_sizes[0] / DIM;
  int E = in_sizes[1];
  if (N <= 0 || E <= 0) return;
  float invN = 1.f / (float)N;
  float invE = 1.f / (float)E;

  // ---- workspace layout ----
  float* ws   = (float*)d_ws;
  float* upd  = ws;                                   // N * 896 floats
  float* x1   = upd + (size_t)N * RD;                 // N * 128 (becomes x2 in-place, then out1)
  float* stats = x1 + (size_t)N * DIM;
  float* s_hv = stats;            // 256
  float* s_x1 = s_hv + 2 * DIM;   // 256
  float* s_he = s_x1 + 2 * DIM;   // 128
  float* qv   = s_he + 2 * DE;    // 128
  float* m1v  = qv + DIM;         // 128
  float* s_up = m1v + DIM;        // 1792
  float* s_o1 = s_up + 2 * RD;    // 256
  float* gram = s_o1 + 2 * DIM;   // 4096 (written fully by gram_reduce)
  float* gcol = gram + DE * DE;   // 64
  float* statsEnd = gcol + DE;
  size_t statsFloats = (size_t)(statsEnd - stats);    // 7104
  // int region (8B-aligned start: preceding float count is even)
  int2* elist2 = (int2*)statsEnd;                     // E int2
  int* cnt    = (int*)(elist2 + E);                   // N   (aliased as excl)
  int* sums   = cnt + N;                              // 1024
  int* base   = sums + 1024;                          // N+1
  int* cursor = base + N + 1;                         // N
  float* parts = upd;                                 // gram partials alias upd (consumed before upd written)

  int nBlk32 = (N + 31) / 32;
  int nch = (N + 255) / 256;

  // zero only atomically-accumulated stats + counts (upd is fully written by fused kernel)
  hipMemsetAsync(stats, 0, statsFloats * sizeof(float), stream);
  hipMemsetAsync(cnt, 0, (size_t)N * sizeof(int), stream);

  // node path
  colstats<DIM, 256><<<512, 256, 0, stream>>>(h_v, N, s_hv);
  mlp128<true, false, true><<<nBlk32, 128, 0, stream>>>(
      h_v, in_W, in_b, in_bn1_g, in_bn1_b, s_hv, invN, N, nullptr, x1, s_x1);
  x2k<<<(N * 32 + 255) / 256, 256, 0, stream>>>(x1, s_x1, in_bn2_g, in_bn2_b, invN, N * 32);

  // edge stats path
  colstats<DE, 256><<<1024, 256, 0, stream>>>(h_e, E, s_he);

  // CSR build
  count_k<<<1024, 256, 0, stream>>>(node_out, E, cnt);
  scan1<<<nch, 256, 0, stream>>>(cnt, N, cnt, sums);
  scan2<<<1, 1024, 0, stream>>>(sums, nch);
  scan3<<<nch, 256, 0, stream>>>(cnt, sums, N, E, base, cursor);
  scatter_k<<<1024, 256, 0, stream>>>(node_out, node_in, rel, E, cursor, elist2);

  // Gram -> analytic edge-bn2 stats (partials aliased on upd, consumed before fused)
  {
    int tiles = 32;
    int P = (E + 32 * tiles - 1) / (32 * tiles);
    gram_kernel<<<P, 256, 0, stream>>>(h_e, E, e_bn1_g, e_bn1_b, s_he, invE, parts, tiles);
    gram_reduce<<<(4160 + 255) / 256, 256, 0, stream>>>(parts, P, gram, gcol);
  }
  ebn2_partial<<<DE, 128, 0, stream>>>(gram, gcol, e_W, invE, qv, m1v);

  // fused sorted-edge GEMM + scatter (no atomics, writes every upd row)
  fused_edge_scatter<<<(N + NPB - 1) / NPB, 128, 0, stream>>>(
      h_e, elist2, base, e_W, e_bn1_g, e_bn1_b, s_he, invE,
      qv, m1v, e_bn2_g, e_bn2_b, x1, N, upd);

  // tail: bn896 -> lin -> bn -> out (+residual)
  colstats<RD, RD><<<448, RD, 0, stream>>>(upd, N, s_up);
  lin_mlp<<<nBlk32, 128, 0, stream>>>(upd, lin_W, lin_bn_g, lin_bn_b, s_up, invN, N,
                                      x1, s_o1);   // x1 reused as out1 (x2 dead after fused)
  mlp128<false, true, false><<<nBlk32, 128, 0, stream>>>(
      x1, out_W, nullptr, out_bn_g, out_bn_b, s_o1, invN, N, h_v, (float*)d_out, nullptr);
}